// Round 12
// baseline (118.097 us; speedup 1.0000x reference)
//
#include <hip/hip_runtime.h>

#define HW_TOTAL (4096 * 4096)
#define NBINS 256
#define NCHUNK (HW_TOTAL / 4)      // int4 chunks = 4M
#define NSUB 16                    // LDS sub-histograms

#define HGRID 256                  // hist blocks: 1/CU
#define HCPT 16                    // chunks per thread (2 halves of 8)
// 256 * 1024 * 16 = 4M exactly.

#define BGRID 512                  // bin blocks: 2/CU (R6-validated geometry)
#define BBATCH 8
// 512 * 1024 * 8 = 4M exactly.

#define BLK 1024

// Measurement round: bin is launched BIN_REPS times (idempotent — identical
// inputs and outputs each launch). bin_dur = (total - 41.96us) / (BIN_REPS-1).
#define BIN_REPS 4

typedef int int4n __attribute__((ext_vector_type(4)));               // aligned 16
typedef int int4a __attribute__((ext_vector_type(4), aligned(4)));   // dword-aligned

// ws layout: +256 B: partials[HGRID][NBINS] (u32). (word 0 unused now.)
#define WS_NEED (HGRID * NBINS * 4 + 256)

// ---------------------------------------------------------------------------
// Otsu threshold from a 256-bin count histogram in LDS, one wave (lane = t).
// Exact uint64 prefix scan via shfl + fp64 inter-class variance argmax
// (val_sum[t] == t*cnt[t] exactly, so only the count histogram is needed).
// ---------------------------------------------------------------------------
__device__ __forceinline__ int otsu_scan64(const unsigned* cnt, int lane) {
    uint4 c4 = ((const uint4*)cnt)[lane];
    unsigned cs[4] = {c4.x, c4.y, c4.z, c4.w};

    unsigned long long lc[4], lv[4];
    unsigned long long ccum = 0ull, vcum = 0ull;
#pragma unroll
    for (int k = 0; k < 4; ++k) {
        ccum += cs[k];
        vcum += (unsigned long long)cs[k] * (unsigned)(4 * lane + k);
        lc[k] = ccum;
        lv[k] = vcum;
    }
    unsigned long long cscan = ccum, vscan = vcum;
    for (int d = 1; d < 64; d <<= 1) {
        unsigned long long cu = __shfl_up(cscan, d);
        unsigned long long vu = __shfl_up(vscan, d);
        if (lane >= d) { cscan += cu; vscan += vu; }
    }
    const unsigned long long cbase = cscan - ccum;
    const unsigned long long vbase = vscan - vcum;
    const unsigned long long vtotal = __shfl(vscan, 63);

    double best = -1.0;
    int bestt = 255;
    const double hw = (double)HW_TOTAL;
    const double vtot_d = (double)vtotal;
#pragma unroll
    for (int k = 0; k < 4; ++k) {
        int tt = 4 * lane + k;
        if (tt > 254) continue;
        double nb = (double)(cbase + lc[k]);
        double sb = (double)(vbase + lv[k]);
        double nw = hw - nb;
        double sw = vtot_d - sb;
        double dm = sb / nb - sw / nw;
        double var = nb * nw * dm * dm;
        if (var > best || (var == best && tt < bestt)) { best = var; bestt = tt; }
    }
    for (int d = 32; d >= 1; d >>= 1) {
        double ov = __shfl_xor(best, d);
        int ot = __shfl_xor(bestt, d);
        if (ov > best || (ov == best && ot < bestt)) { best = ov; bestt = ot; }
    }
    return bestt;
}

// ---------------------------------------------------------------------------
// Kernel 1 (unchanged from R10/R11): histogram. 16 LDS sub-hists
// h[sub*256+bin] (bank = bin mod 32 -> all 32 banks, ~2-way = free). Two
// 8-deep int4 batches. Flush: one partial row per block. MODE 1: atomic
// flush fallback.
// ---------------------------------------------------------------------------
template <int MODE>
__global__ __launch_bounds__(BLK, 8) void otsu_hist_k(const int4* __restrict__ img4,
                                                      unsigned* __restrict__ out) {
    __shared__ unsigned h[NSUB * NBINS];    // 16 KiB
    const int t = threadIdx.x;
    for (int i = t; i < NSUB * NBINS; i += BLK) h[i] = 0;
    __syncthreads();

    unsigned* hp = h + ((t & (NSUB - 1)) << 8);
    const int wave = t >> 6, lane = t & 63;
    const int i0 = blockIdx.x * (BLK * HCPT) + wave * (64 * HCPT) + lane;

#pragma unroll
    for (int half = 0; half < 2; ++half) {
        int4 v[8];
        const int j0 = i0 + half * (8 * 64);
#pragma unroll
        for (int k = 0; k < 8; ++k) v[k] = img4[j0 + k * 64];
#pragma unroll
        for (int k = 0; k < 8; ++k) {
            atomicAdd(&hp[(unsigned)v[k].x], 1u);
            atomicAdd(&hp[(unsigned)v[k].y], 1u);
            atomicAdd(&hp[(unsigned)v[k].z], 1u);
            atomicAdd(&hp[(unsigned)v[k].w], 1u);
        }
    }
    __syncthreads();

    if (t < NBINS) {
        unsigned s = 0;
#pragma unroll
        for (int ss = 0; ss < NSUB; ++ss) s += h[(ss << 8) | t];
        if (MODE == 0) {
            out[blockIdx.x * NBINS + t] = s;
        } else {
            if (s) atomicAdd(&out[t], s);
        }
    }
}

// ---------------------------------------------------------------------------
// Kernel 2 (unchanged from R11): threshold + binarize. Prologue: every block
// redundantly reduces the B partial rows and wave 0 runs the scan; then
// binarize with dword-aligned unaligned dwordx4 loads (pixels 4c-1..4c+2)
// and 16 B-aligned nontemporal stores. Idempotent -> safe to replicate.
// ---------------------------------------------------------------------------
__global__ __launch_bounds__(BLK, 8) void otsu_bin_k(const int* __restrict__ img,
                                                     int* __restrict__ out,
                                                     const unsigned* __restrict__ partials,
                                                     int B) {
    __shared__ unsigned red[4][NBINS];
    __shared__ unsigned cnt[NBINS];
    __shared__ int s_thresh;

    const int t = threadIdx.x;
    const int bin = t & 255;
    const int q = t >> 8;
    const int BQ = (B + 3) / 4;
    {
        int r = q * BQ;
        const int e = min((q + 1) * BQ, B);
        unsigned s = 0;
        for (; r + 16 <= e; r += 16) {
#pragma unroll
            for (int k = 0; k < 16; ++k) s += partials[(r + k) * NBINS + bin];
        }
        for (; r < e; ++r) s += partials[r * NBINS + bin];
        red[q][bin] = s;
    }
    __syncthreads();
    if (t < NBINS)
        cnt[bin] = red[0][bin] + red[1][bin] + red[2][bin] + red[3][bin];
    __syncthreads();
    if (t < 64) {
        int bt = otsu_scan64(cnt, t);
        if (t == 0) s_thresh = bt;
    }
    __syncthreads();
    const int thresh = s_thresh;

    const int wave = t >> 6, lane = t & 63;
    const int i0 = blockIdx.x * (BLK * BBATCH) + wave * (64 * BBATCH) + lane;
#pragma unroll
    for (int k = 0; k < BBATCH; ++k) {
        const int c = i0 + k * 64;
        int4a v = *(const int4a*)(img + (c ? 4 * c - 1 : 0));  // pixels 4c-1..4c+2
        int4n o;
        o.x = (v.x <= thresh) ? 0 : 256;
        o.y = (v.y <= thresh) ? 0 : 256;
        o.z = (v.z <= thresh) ? 0 : 256;
        o.w = (v.w <= thresh) ? 0 : 256;
        if (c == 0) { o.w = o.z; o.z = o.y; o.y = o.x; o.x = thresh; }
        __builtin_nontemporal_store(o, (int4n*)out + c);
    }
    if (i0 == 0)
        out[HW_TOTAL] = (img[HW_TOTAL - 1] <= thresh) ? 0 : 256;
}

extern "C" void kernel_launch(void* const* d_in, const int* in_sizes, int n_in,
                              void* d_out, int out_size, void* d_ws, size_t ws_size,
                              hipStream_t stream) {
    const int* img = (const int*)d_in[0];
    int* out = (int*)d_out;
    unsigned* hist_buf = (unsigned*)((char*)d_ws + 256);

    if (ws_size >= (size_t)WS_NEED) {
        otsu_hist_k<0><<<HGRID, BLK, 0, stream>>>((const int4*)img, hist_buf);
        // Measurement: BIN_REPS identical (idempotent) bin launches.
        // bin_dur = (total - R11_total) / (BIN_REPS - 1).
        for (int rep = 0; rep < BIN_REPS; ++rep)
            otsu_bin_k<<<BGRID, BLK, 0, stream>>>(img, out, hist_buf, HGRID);
    } else {
        (void)hipMemsetAsync(hist_buf, 0, NBINS * sizeof(unsigned), stream);
        otsu_hist_k<1><<<HGRID, BLK, 0, stream>>>((const int4*)img, hist_buf);
        otsu_bin_k<<<BGRID, BLK, 0, stream>>>(img, out, hist_buf, 1);
    }
}

// Round 13
// 42.918 us; speedup vs baseline: 2.7517x; 2.7517x over previous
//
#include <hip/hip_runtime.h>

#define HW_TOTAL (4096 * 4096)
#define NBINS 256
#define NCHUNK (HW_TOTAL / 4)      // int4 chunks = 4M
#define NSUB 16                    // LDS sub-histograms

#define HGRID 512                  // hist blocks: 2/CU (32 waves/CU)
#define HCPT 8                     // chunks per thread (one 8-deep batch)
// 512 * 1024 * 8 = 4M exactly. Max pixels/block = 1024*8*4 = 32768 < 65536 -> u16 partials.

#define BGRID 256                  // bin blocks: 1/CU, 16 chunks/thread
#define BBATCH 16                  // two 8-deep halves
// 256 * 1024 * 16 = 4M exactly.

#define BLK 1024

typedef int int4n __attribute__((ext_vector_type(4)));               // aligned 16
typedef int int4a __attribute__((ext_vector_type(4), aligned(4)));   // dword-aligned

// ws layout: +256 B: partials u16[HGRID][NBINS] (256 KB). Fallback: u32 ghist.
#define WS_NEED (HGRID * NBINS * 2 + 256)

// ---------------------------------------------------------------------------
// Otsu threshold from a 256-bin count histogram in LDS, one wave (lane = t).
// Exact uint64 prefix scan via shfl + fp64 inter-class variance argmax
// (val_sum[t] == t*cnt[t] exactly, so only the count histogram is needed).
// ---------------------------------------------------------------------------
__device__ __forceinline__ int otsu_scan64(const unsigned* cnt, int lane) {
    uint4 c4 = ((const uint4*)cnt)[lane];
    unsigned cs[4] = {c4.x, c4.y, c4.z, c4.w};

    unsigned long long lc[4], lv[4];
    unsigned long long ccum = 0ull, vcum = 0ull;
#pragma unroll
    for (int k = 0; k < 4; ++k) {
        ccum += cs[k];
        vcum += (unsigned long long)cs[k] * (unsigned)(4 * lane + k);
        lc[k] = ccum;
        lv[k] = vcum;
    }
    unsigned long long cscan = ccum, vscan = vcum;
    for (int d = 1; d < 64; d <<= 1) {
        unsigned long long cu = __shfl_up(cscan, d);
        unsigned long long vu = __shfl_up(vscan, d);
        if (lane >= d) { cscan += cu; vscan += vu; }
    }
    const unsigned long long cbase = cscan - ccum;
    const unsigned long long vbase = vscan - vcum;
    const unsigned long long vtotal = __shfl(vscan, 63);

    double best = -1.0;
    int bestt = 255;
    const double hw = (double)HW_TOTAL;
    const double vtot_d = (double)vtotal;
#pragma unroll
    for (int k = 0; k < 4; ++k) {
        int tt = 4 * lane + k;
        if (tt > 254) continue;
        double nb = (double)(cbase + lc[k]);
        double sb = (double)(vbase + lv[k]);
        double nw = hw - nb;
        double sw = vtot_d - sb;
        double dm = sb / nb - sw / nw;
        double var = nb * nw * dm * dm;
        if (var > best || (var == best && tt < bestt)) { best = var; bestt = tt; }
    }
    for (int d = 32; d >= 1; d >>= 1) {
        double ov = __shfl_xor(best, d);
        int ot = __shfl_xor(bestt, d);
        if (ov > best || (ov == best && ot < bestt)) { best = ov; bestt = ot; }
    }
    return bestt;
}

// ---------------------------------------------------------------------------
// Kernel 1: histogram. 16 LDS sub-hists h[sub*256+bin] (bank = bin mod 32 ->
// all 32 banks, ~2-way = free). One 8-deep int4 batch per thread; 2 blocks/CU
// for 32 waves/CU of load-stream TLP. Flush: one u16 partial row per block
// (max block count 32768 fits u16). MODE 1: u32 global atomic fallback.
// ---------------------------------------------------------------------------
template <int MODE>
__global__ __launch_bounds__(BLK, 8) void otsu_hist_k(const int4* __restrict__ img4,
                                                      unsigned short* __restrict__ pout,
                                                      unsigned* __restrict__ ghist) {
    __shared__ unsigned h[NSUB * NBINS];    // 16 KiB
    const int t = threadIdx.x;
    for (int i = t; i < NSUB * NBINS; i += BLK) h[i] = 0;
    __syncthreads();

    unsigned* hp = h + ((t & (NSUB - 1)) << 8);
    const int wave = t >> 6, lane = t & 63;
    const int i0 = blockIdx.x * (BLK * HCPT) + wave * (64 * HCPT) + lane;

    int4 v[HCPT];
#pragma unroll
    for (int k = 0; k < HCPT; ++k) v[k] = img4[i0 + k * 64];
#pragma unroll
    for (int k = 0; k < HCPT; ++k) {
        atomicAdd(&hp[(unsigned)v[k].x], 1u);
        atomicAdd(&hp[(unsigned)v[k].y], 1u);
        atomicAdd(&hp[(unsigned)v[k].z], 1u);
        atomicAdd(&hp[(unsigned)v[k].w], 1u);
    }
    __syncthreads();

    if (t < NBINS) {
        unsigned s = 0;
#pragma unroll
        for (int ss = 0; ss < NSUB; ++ss) s += h[(ss << 8) | t];
        if (MODE == 0) {
            pout[blockIdx.x * NBINS + t] = (unsigned short)s;
        } else {
            if (s) atomicAdd(&ghist[t], s);
        }
    }
}

// ---------------------------------------------------------------------------
// Kernel 2: threshold + binarize. Prologue: every block reduces the u16
// partials (thread (bin,q) sums 128 rows, coalesced 2B loads, u32 accum),
// wave 0 runs the exact scan + fp64 argmax, LDS broadcast. Main: out image
// lives at out[1..HW]; aligned out-chunk out[4c..4c+3] needs pixels
// [4c-1..4c+2], loaded as dword-aligned dwordx4 (L3-hit); 16 B-aligned
// nontemporal stores. U16SRC=0 fallback reads a u32 ghist directly.
// ---------------------------------------------------------------------------
template <int U16SRC>
__global__ __launch_bounds__(BLK, 8) void otsu_bin_k(const int* __restrict__ img,
                                                     int* __restrict__ out,
                                                     const unsigned short* __restrict__ partials,
                                                     const unsigned* __restrict__ ghist) {
    __shared__ unsigned red[4][NBINS];
    __shared__ unsigned cnt[NBINS];
    __shared__ int s_thresh;

    const int t = threadIdx.x;
    if (U16SRC) {
        const int bin = t & 255;
        const int q = t >> 8;              // 4 quarters x 128 rows
        unsigned s = 0;
        for (int r = q * 128; r < q * 128 + 128; r += 16) {
#pragma unroll
            for (int k = 0; k < 16; ++k) s += partials[(r + k) * NBINS + bin];
        }
        red[q][bin] = s;
        __syncthreads();
        if (t < NBINS)
            cnt[bin] = red[0][bin] + red[1][bin] + red[2][bin] + red[3][bin];
        __syncthreads();
    } else {
        if (t < NBINS) cnt[t] = ghist[t];
        __syncthreads();
    }
    if (t < 64) {
        int bt = otsu_scan64(cnt, t);
        if (t == 0) s_thresh = bt;
    }
    __syncthreads();
    const int thresh = s_thresh;

    const int wave = t >> 6, lane = t & 63;
    const int i0 = blockIdx.x * (BLK * BBATCH) + wave * (64 * BBATCH) + lane;
#pragma unroll
    for (int k = 0; k < BBATCH; ++k) {
        const int c = i0 + k * 64;
        int4a v = *(const int4a*)(img + (c ? 4 * c - 1 : 0));  // pixels 4c-1..4c+2
        int4n o;
        o.x = (v.x <= thresh) ? 0 : 256;
        o.y = (v.y <= thresh) ? 0 : 256;
        o.z = (v.z <= thresh) ? 0 : 256;
        o.w = (v.w <= thresh) ? 0 : 256;
        if (c == 0) { o.w = o.z; o.z = o.y; o.y = o.x; o.x = thresh; }
        __builtin_nontemporal_store(o, (int4n*)out + c);
    }
    if (i0 == 0)
        out[HW_TOTAL] = (img[HW_TOTAL - 1] <= thresh) ? 0 : 256;
}

extern "C" void kernel_launch(void* const* d_in, const int* in_sizes, int n_in,
                              void* d_out, int out_size, void* d_ws, size_t ws_size,
                              hipStream_t stream) {
    const int* img = (const int*)d_in[0];
    int* out = (int*)d_out;
    unsigned short* part16 = (unsigned short*)((char*)d_ws + 256);
    unsigned* ghist = (unsigned*)((char*)d_ws + 256);

    if (ws_size >= (size_t)WS_NEED) {
        // 2-node path: hist (u16 partial rows) -> thresh+bin.
        otsu_hist_k<0><<<HGRID, BLK, 0, stream>>>((const int4*)img, part16, nullptr);
        otsu_bin_k<1><<<BGRID, BLK, 0, stream>>>(img, out, part16, nullptr);
    } else {
        // fallback: atomic flush into a single u32 256-bin histogram
        (void)hipMemsetAsync(ghist, 0, NBINS * sizeof(unsigned), stream);
        otsu_hist_k<1><<<HGRID, BLK, 0, stream>>>((const int4*)img, nullptr, ghist);
        otsu_bin_k<0><<<BGRID, BLK, 0, stream>>>(img, out, nullptr, ghist);
    }
}